// Round 12
// baseline (90.236 us; speedup 1.0000x reference)
//
#include <hip/hip_runtime.h>

constexpr int NN = 40000;
constexpr int NE = 640000;
constexpr int NBKT = 313;      // bucket = dst >> 7, 128 nodes per bucket (last: 64)
constexpr int CBLK = 128;      // count/scatter blocks; 128*5000 == NE

typedef __attribute__((ext_vector_type(8))) short short8;
typedef __attribute__((ext_vector_type(4))) float f32x4;
typedef __attribute__((ext_vector_type(2))) float f32x2;

// f32 -> bf16 round-to-nearest-even
__device__ __forceinline__ unsigned short rneb(float f) {
    unsigned u = __float_as_uint(f);
    u = (u + 0x7FFFu + ((u >> 16) & 1u)) >> 16;
    return (unsigned short)u;
}
__device__ __forceinline__ float b2f(unsigned short s) {
    return __uint_as_float(((unsigned)s) << 16);
}

// ---------------- fp8 e4m3 pack/unpack (HW cvt if available) ----------------
#if defined(__has_builtin)
#if __has_builtin(__builtin_amdgcn_cvt_pk_f32_fp8) && __has_builtin(__builtin_amdgcn_cvt_pk_fp8_f32)
#define FP8_HW 1
#endif
#endif

#ifndef FP8_HW
__device__ __forceinline__ unsigned char f32_to_fp8_sw(float f) {
    float a = fabsf(f);
    unsigned s = (f < 0.f) ? 0x80u : 0u;
    if (a > 448.f) a = 448.f;
    unsigned char r;
    if (a < 0.015625f) {
        int m = (int)rintf(a * 512.f);
        r = (m >= 8) ? (unsigned char)0x08 : (unsigned char)m;
    } else {
        unsigned u = __float_as_uint(a);
        u += 0x0007FFFFu + ((u >> 20) & 1u);
        int e8 = (int)((u >> 23) & 0xFF) - 127 + 7;
        unsigned m = (u >> 20) & 7u;
        if (e8 > 15 || (e8 == 15 && m == 7)) { e8 = 15; m = 6; }
        r = (unsigned char)((e8 << 3) | m);
    }
    return r | (unsigned char)s;
}
__device__ __forceinline__ float fp8_to_f32_sw(unsigned char b) {
    unsigned s = (b >> 7) & 1u, e = (b >> 3) & 0xFu, m = b & 7u;
    float v = e ? ldexpf((float)(8 + m), (int)e - 10) : ldexpf((float)m, -9);
    return s ? -v : v;
}
#endif

__device__ __forceinline__ unsigned pack_fp8x4(float4 v) {
#ifdef FP8_HW
    unsigned r = __builtin_amdgcn_cvt_pk_fp8_f32(v.x, v.y, 0, false);
    r = __builtin_amdgcn_cvt_pk_fp8_f32(v.z, v.w, (int)r, true);
    return r;
#else
    return (unsigned)f32_to_fp8_sw(v.x) | ((unsigned)f32_to_fp8_sw(v.y) << 8)
         | ((unsigned)f32_to_fp8_sw(v.z) << 16) | ((unsigned)f32_to_fp8_sw(v.w) << 24);
#endif
}

__device__ __forceinline__ void unpack_fp8x4(unsigned u, float* o) {
#ifdef FP8_HW
    f32x2 d0 = __builtin_amdgcn_cvt_pk_f32_fp8(u, false);
    f32x2 d1 = __builtin_amdgcn_cvt_pk_f32_fp8(u, true);
    o[0] = d0[0]; o[1] = d0[1]; o[2] = d1[0]; o[3] = d1[1];
#else
    o[0] = fp8_to_f32_sw((unsigned char)(u & 0xFF));
    o[1] = fp8_to_f32_sw((unsigned char)((u >> 8) & 0xFF));
    o[2] = fp8_to_f32_sw((unsigned char)((u >> 16) & 0xFF));
    o[3] = fp8_to_f32_sw((unsigned char)((u >> 24) & 0xFF));
#endif
}

// ---------- K1: fused cvtx(bf16 + fp8) + cvtW + per-block bucket counts ----------
__global__ __launch_bounds__(1024) void prep_k(const float* __restrict__ x,
                                               unsigned short* __restrict__ xb,
                                               unsigned* __restrict__ x8w,
                                               const float* __restrict__ W,
                                               unsigned short* __restrict__ Wb,
                                               const int* __restrict__ dst,
                                               int* __restrict__ gcnt2) {
    __shared__ int cnt[NBKT];
    int bid = blockIdx.x, t = threadIdx.x;
    if (bid < 1250) {                            // x: 1250*1024 == NN*32 f4-groups
        int g = bid * 1024 + t;
        float4 v = reinterpret_cast<const float4*>(x)[g];
        ushort4 o = { rneb(v.x), rneb(v.y), rneb(v.z), rneb(v.w) };
        reinterpret_cast<ushort4*>(xb)[g] = o;
        x8w[g] = pack_fp8x4(v);                  // fp8 copy for the gather
    } else if (bid < 1258) {                     // W: 8*1024 == 128*256/4 f4-groups
        int g = (bid - 1250) * 1024 + t;
        float4 v = reinterpret_cast<const float4*>(W)[g];
        ushort4 o = { rneb(v.x), rneb(v.y), rneb(v.z), rneb(v.w) };
        reinterpret_cast<ushort4*>(Wb)[g] = o;
    } else {                                     // counts: 128 blocks x 5000 edges
        int cb = bid - 1258;
        if (t < NBKT) cnt[t] = 0;
        __syncthreads();
        int eb = cb * 5000;
        for (int i = t; i < 5000; i += 1024)
            atomicAdd(&cnt[dst[eb + i] >> 7], 1);
        __syncthreads();
        if (t < NBKT) gcnt2[cb * 320 + t] = cnt[t];
    }
}

// ---------- K2: sum per-block counts + exclusive scan -> bptr[314], cursor[313] ----------
__global__ __launch_bounds__(1024) void cscan_k(const int* __restrict__ gcnt2,
                                                int* __restrict__ bptr,
                                                int* __restrict__ cursor) {
    __shared__ int sc[1024];
    int t = threadIdx.x;
    int c = 0;
    if (t < NBKT)
        for (int b = 0; b < CBLK; ++b) c += gcnt2[b * 320 + t];
    sc[t] = c;
    __syncthreads();
    for (int o = 1; o < 1024; o <<= 1) {
        int u = (t >= o) ? sc[t - o] : 0;
        __syncthreads();
        sc[t] += u;
        __syncthreads();
    }
    if (t < NBKT) {
        int excl = sc[t] - c;
        bptr[t]   = excl;
        cursor[t] = excl;
    }
    if (t == 0) bptr[NBKT] = NE;
}

// ---------- K3: bucket scatter: rec {src u16 | ew f16}, dloc u8 = dst&127 ----------
__global__ __launch_bounds__(1024) void cscatter_k(const int* __restrict__ dst,
                                                   const int* __restrict__ src,
                                                   const float* __restrict__ ew,
                                                   const int* __restrict__ gcnt2,
                                                   int* __restrict__ cursor,
                                                   unsigned* __restrict__ rec,
                                                   unsigned char* __restrict__ dloc) {
    __shared__ int cnt[NBKT];
    __shared__ int base[NBKT];
    int t = threadIdx.x;
    int cb = blockIdx.x;
    if (t < NBKT) {
        int c = gcnt2[cb * 320 + t];             // counted in prep_k
        base[t] = c ? atomicAdd(&cursor[t], c) : 0;
        cnt[t] = 0;                              // local cursor
    }
    __syncthreads();
    int eb = cb * 5000;
    for (int i = t; i < 5000; i += 1024) {
        int d   = dst[eb + i];
        int bkt = d >> 7;
        int slot = atomicAdd(&cnt[bkt], 1);
        int p = base[bkt] + slot;
        unsigned short wh = __builtin_bit_cast(unsigned short, (_Float16)ew[eb + i]);
        rec[p]  = (unsigned)src[eb + i] | ((unsigned)wh << 16);
        dloc[p] = (unsigned char)(d & 127);
    }
}

// ---------- K4: fused aggregate + MFMA GEMM, one block per 128-node bucket ----------
// Geometry fix for R7-R11's scheduling tail: 313 blocks x 16 waves = 5008 waves
// (fits ~1 generation) vs 625x16 = 10000 (2.4 generations at the measured ~1
// resident block/CU). Phase 1: in-LDS regroup by node (128 groups x 8 lanes,
// uint4 = full 128B fp8 row per group, unroll-2). Phase 2: 128x256x128 MFMA.
__global__ __launch_bounds__(1024) void aggemm_k(const unsigned* __restrict__ rec,
                                                 const unsigned char* __restrict__ dloc,
                                                 const int* __restrict__ bptr,
                                                 const unsigned short* __restrict__ xb,
                                                 const unsigned char* __restrict__ x8,
                                                 const unsigned short* __restrict__ Wb,
                                                 const float* __restrict__ bias_p,
                                                 float* __restrict__ out) {
    constexpr int CAP = 3072;                    // mean bucket = 2045, sigma 45 -> 1 chunk
    __shared__ unsigned grec[CAP];
    __shared__ int cnt[128];
    __shared__ int cur[128];
    __shared__ int pL[129];
    __shared__ int wtot[2];
    __shared__ unsigned short hbl[128 * 128];    // swizzled agg half, 32 KB
    int bkt = blockIdx.x, t = threadIdx.x;
    int beg = bptr[bkt], end = bptr[bkt + 1];
    int grp = t >> 3, fl = t & 7;                // 128 node-groups x 8 feature-lanes
    const uint4* xv = reinterpret_cast<const uint4*>(x8);   // row = 128B = 8 uint4
    float acc[16];
    #pragma unroll
    for (int i = 0; i < 16; ++i) acc[i] = 0.f;
    float wsv = 0.f;

    for (int cb = beg; cb < end; cb += CAP) {
        int m = end - cb; if (m > CAP) m = CAP;
        if (t < 128) cnt[t] = 0;
        __syncthreads();
        unsigned rr[3]; int dd[3];
        #pragma unroll
        for (int j = 0; j < 3; ++j) {
            dd[j] = -1;
            int i = t + j * 1024;
            if (i < m) {
                rr[j] = rec[cb + i];
                dd[j] = dloc[cb + i];
                atomicAdd(&cnt[dd[j]], 1);
            }
        }
        __syncthreads();
        int wv = t >> 6, ln = t & 63;
        int sv = 0, sincl = 0;
        if (wv < 2) {                            // 2 waves scan 128 counters
            sv = cnt[wv * 64 + ln];
            sincl = sv;
            #pragma unroll
            for (int o = 1; o < 64; o <<= 1) {
                int u = __shfl_up(sincl, o);
                if (ln >= o) sincl += u;
            }
            if (ln == 63) wtot[wv] = sincl;
        }
        __syncthreads();
        if (wv < 2) {
            int off = (wv == 1) ? wtot[0] : 0;
            int idx = wv * 64 + ln;
            int excl = off + sincl - sv;
            pL[idx]  = excl;
            cur[idx] = excl;
        }
        if (t == 0) pL[128] = m;
        __syncthreads();
        #pragma unroll
        for (int j = 0; j < 3; ++j)
            if (dd[j] >= 0) { int p = atomicAdd(&cur[dd[j]], 1); grec[p] = rr[j]; }
        __syncthreads();
        int gb = pL[grp], ge = pL[grp + 1];
        int e = gb;
        for (; e + 2 <= ge; e += 2) {            // unroll-2: 2 row-gathers in flight
            unsigned q0 = grec[e], q1 = grec[e + 1];
            uint4 a0 = xv[(size_t)(q0 & 0xFFFF) * 8 + fl];
            uint4 a1 = xv[(size_t)(q1 & 0xFFFF) * 8 + fl];
            float w0 = (float)__builtin_bit_cast(_Float16, (unsigned short)(q0 >> 16));
            float w1 = (float)__builtin_bit_cast(_Float16, (unsigned short)(q1 >> 16));
            wsv += w0 + w1;
            float f[16];
            unpack_fp8x4(a0.x, f); unpack_fp8x4(a0.y, f + 4);
            unpack_fp8x4(a0.z, f + 8); unpack_fp8x4(a0.w, f + 12);
            #pragma unroll
            for (int i = 0; i < 16; ++i) acc[i] += w0 * f[i];
            unpack_fp8x4(a1.x, f); unpack_fp8x4(a1.y, f + 4);
            unpack_fp8x4(a1.z, f + 8); unpack_fp8x4(a1.w, f + 12);
            #pragma unroll
            for (int i = 0; i < 16; ++i) acc[i] += w1 * f[i];
        }
        if (e < ge) {                            // remainder
            unsigned q = grec[e];
            uint4 a = xv[(size_t)(q & 0xFFFF) * 8 + fl];
            float w = (float)__builtin_bit_cast(_Float16, (unsigned short)(q >> 16));
            wsv += w;
            float f[16];
            unpack_fp8x4(a.x, f); unpack_fp8x4(a.y, f + 4);
            unpack_fp8x4(a.z, f + 8); unpack_fp8x4(a.w, f + 12);
            #pragma unroll
            for (int i = 0; i < 16; ++i) acc[i] += w * f[i];
        }
        __syncthreads();                         // protect grec/cnt for next chunk
    }

    {   // write node grp's agg slice (2x short8, bf16) into swizzled LDS
        int n = bkt * 128 + grp;
        if (n < NN) {
            float inv = 1.f / fmaxf(wsv, 1e-8f);
            short8 o0, o1;
            #pragma unroll
            for (int i = 0; i < 8; ++i) { o0[i] = (short)rneb(acc[i] * inv); o1[i] = (short)rneb(acc[i + 8] * inv); }
            int s = grp & 7;                     // granule swizzle (16 granules x 8B per row)
            *reinterpret_cast<short8*>(&hbl[grp * 128 + ((2 * fl) ^ s) * 8])     = o0;
            *reinterpret_cast<short8*>(&hbl[grp * 128 + ((2 * fl + 1) ^ s) * 8]) = o1;
        }
    }
    __syncthreads();

    // ---- phase 2: MFMA: 8 row-tiles x 8 col-tiles, 16 waves x 4 tiles ----
    int w = t >> 6, l = t & 63;
    int l15 = l & 15, lg = l >> 4;
    int rt = w & 7, cq = w >> 3;                 // row-tile 0..7; col-half 0..1
    f32x4 acc2[4] = { (f32x4)0.f, (f32x4)0.f, (f32x4)0.f, (f32x4)0.f };
    float bias2[4];
    #pragma unroll
    for (int q = 0; q < 4; ++q) bias2[q] = bias_p[(cq * 4 + q) * 16 + l15];
    int arow = bkt * 128 + rt * 16 + l15;
    if (arow > NN - 1) arow = NN - 1;

    #pragma unroll
    for (int step = 0; step < 8; ++step) {
        short8 a;
        if (step < 4) {
            a = *reinterpret_cast<const short8*>(xb + (size_t)arow * 128 + step * 32 + lg * 8);
        } else {
            int r = rt * 16 + l15;
            int g = (step - 4) * 4 + lg;         // granule 0..15 in agg half
            a = *reinterpret_cast<const short8*>(&hbl[r * 128 + (g ^ (r & 7)) * 8]);
        }
        #pragma unroll
        for (int q = 0; q < 4; ++q) {
            int ct = cq * 4 + q;
            short8 bf = *reinterpret_cast<const short8*>(Wb + (size_t)(ct * 16 + l15) * 256 + step * 32 + lg * 8);
            acc2[q] = __builtin_amdgcn_mfma_f32_16x16x32_bf16(a, bf, acc2[q], 0, 0, 0);
        }
    }

    #pragma unroll
    for (int q = 0; q < 4; ++q)
        #pragma unroll
        for (int r4 = 0; r4 < 4; ++r4) {
            int row = bkt * 128 + rt * 16 + lg * 4 + r4;
            if (row < NN)
                out[(size_t)row * 128 + (cq * 4 + q) * 16 + l15] = acc2[q][r4] + bias2[q];
        }
}

// ==================== fallback path (small ws): atomic scatter + f32 GEMM ====================

__global__ void wsum_k(const int* __restrict__ dst, const float* __restrict__ ew,
                       float* __restrict__ wsum) {
    int e = blockIdx.x * 256 + threadIdx.x;
    if (e < NE) atomicAdd(&wsum[dst[e]], ew[e]);
}

__global__ void zerof_k(float* __restrict__ p, int n4) {
    int g = blockIdx.x * 256 + threadIdx.x;
    if (g < n4) reinterpret_cast<float4*>(p)[g] = make_float4(0.f, 0.f, 0.f, 0.f);
}

__global__ void scatter_k(const int* __restrict__ src, const int* __restrict__ dst,
                          const float* __restrict__ ew, const float* __restrict__ wsum,
                          const float* __restrict__ x, float* __restrict__ agg) {
    int tid = blockIdx.x * 256 + threadIdx.x;
    int e = tid >> 5;
    int p = tid & 31;
    if (e >= NE) return;
    int s = src[e], dn = dst[e];
    float wn = ew[e] / fmaxf(wsum[dn], 1e-8f);
    float4 v = *reinterpret_cast<const float4*>(x + (size_t)s * 128 + p * 4);
    float* o = agg + (size_t)dn * 128 + p * 4;
    atomicAdd(o + 0, wn * v.x);
    atomicAdd(o + 1, wn * v.y);
    atomicAdd(o + 2, wn * v.z);
    atomicAdd(o + 3, wn * v.w);
}

__global__ __launch_bounds__(256) void gemm_f32_k(const float* __restrict__ x,
                                                  const float* __restrict__ agg,
                                                  const float* __restrict__ W,
                                                  const float* __restrict__ b,
                                                  float* __restrict__ out) {
    __shared__ float4 Wl[128 * 64];
    __shared__ float4 hl[16 * 64];
    int t = threadIdx.x;
    int base = blockIdx.x * 80;
    const float4* Wg = reinterpret_cast<const float4*>(W);
    #pragma unroll
    for (int i = 0; i < 32; ++i) {
        int f = t + i * 256;
        int r = f >> 6, kk = f & 63;
        Wl[r * 64 + (kk ^ (r & 7))] = Wg[f];
    }
    int jj = t & 63, wsl = t >> 6, sw = jj & 7;
    float bv[2] = { b[jj], b[jj + 64] };
    const float4* xg = reinterpret_cast<const float4*>(x);
    const float4* ag = reinterpret_cast<const float4*>(agg);
    for (int g = 0; g < 5; ++g) {
        int nbase = base + g * 16;
        __syncthreads();
        #pragma unroll
        for (int i = 0; i < 4; ++i) {
            int f = t + i * 256;
            int ln = f >> 6, kk = f & 63;
            size_t node = (size_t)(nbase + ln);
            hl[ln * 64 + kk] = (kk < 32) ? xg[node * 32 + kk] : ag[node * 32 + (kk - 32)];
        }
        __syncthreads();
        float acc[2][4];
        #pragma unroll
        for (int q = 0; q < 2; ++q)
            #pragma unroll
            for (int n = 0; n < 4; ++n) acc[q][n] = 0.f;
        #pragma unroll 4
        for (int kk = 0; kk < 64; ++kk) {
            float4 h[4];
            #pragma unroll
            for (int n = 0; n < 4; ++n) h[n] = hl[(wsl + 4 * n) * 64 + kk];
            #pragma unroll
            for (int q = 0; q < 2; ++q) {
                float4 wvv = Wl[(jj + q * 64) * 64 + (kk ^ sw)];
                #pragma unroll
                for (int n = 0; n < 4; ++n)
                    acc[q][n] += wvv.x * h[n].x + wvv.y * h[n].y + wvv.z * h[n].z + wvv.w * h[n].w;
            }
        }
        #pragma unroll
        for (int q = 0; q < 2; ++q)
            #pragma unroll
            for (int n = 0; n < 4; ++n)
                out[(size_t)(nbase + wsl + 4 * n) * 128 + jj + q * 64] = acc[q][n] + bv[q];
    }
}

extern "C" void kernel_launch(void* const* d_in, const int* in_sizes, int n_in,
                              void* d_out, int out_size, void* d_ws, size_t ws_size,
                              hipStream_t stream) {
    const float* x  = (const float*)d_in[0];
    const int*   ei = (const int*)d_in[1];
    const float* ew = (const float*)d_in[2];
    const float* W  = (const float*)d_in[3];
    const float* b  = (const float*)d_in[4];
    float* out = (float*)d_out;
    const int* src = ei;
    const int* dst = ei + NE;

    // ws layout (bytes):
    //   0        : bptr [314 int]
    //   4096     : cursor [313 int]
    //   8192     : gcnt2 [128][320] int (163840) -> ends 172032
    //   172032   : Wb [128x256 bf16] (64 KB)
    //   237568   : dloc [640000 u8]
    //   880640   : rec [640000 u32] (2.56 MB)
    //   3670016  : xb [40000][128] bf16 (10.24 MB)
    //   13910016 : x8 [40000][128] fp8 (5.12 MB) -> need ~18.2 MB (proven in R11)
    const size_t off_cursor = 4096;
    const size_t off_gcnt2  = 8192;
    const size_t off_Wb     = 172032;
    const size_t off_dloc   = 237568;
    const size_t off_rec    = 880640;
    const size_t off_xb     = 3670016;
    const size_t off_x8     = 13910016;
    const size_t need = off_x8 + (size_t)NN * 128;

    if (ws_size >= need) {
        int* bptr   = (int*)d_ws;
        int* cursor = (int*)((char*)d_ws + off_cursor);
        int* gcnt2  = (int*)((char*)d_ws + off_gcnt2);
        unsigned short* Wb = (unsigned short*)((char*)d_ws + off_Wb);
        unsigned char* dloc = (unsigned char*)((char*)d_ws + off_dloc);
        unsigned* rec = (unsigned*)((char*)d_ws + off_rec);
        unsigned short* xb = (unsigned short*)((char*)d_ws + off_xb);
        unsigned char* x8 = (unsigned char*)((char*)d_ws + off_x8);

        prep_k    <<<1386, 1024, 0, stream>>>(x, xb, (unsigned*)x8, W, Wb, dst, gcnt2);
        cscan_k   <<<1, 1024, 0, stream>>>(gcnt2, bptr, cursor);
        cscatter_k<<<CBLK, 1024, 0, stream>>>(dst, src, ew, gcnt2, cursor, rec, dloc);
        aggemm_k  <<<NBKT, 1024, 0, stream>>>(rec, dloc, bptr, xb, x8, Wb, b, out);
    } else {
        float* wsum = (float*)d_ws;
        float* agg  = out;
        zerof_k  <<<(NN / 4 + 255) / 256, 256, 0, stream>>>(wsum, NN / 4);
        zerof_k  <<<(NN * 32 + 255) / 256, 256, 0, stream>>>(agg, NN * 32);
        wsum_k   <<<(NE + 255) / 256, 256, 0, stream>>>(dst, ew, wsum);
        scatter_k<<<NE * 32 / 256, 256, 0, stream>>>(src, dst, ew, wsum, x, agg);
        gemm_f32_k<<<500, 256, 0, stream>>>(x, agg, W, b, out);
    }
}